// Round 5
// baseline (852.007 us; speedup 1.0000x reference)
//
#include <hip/hip_runtime.h>
#include <stdint.h>

// Fused multi-scale ROIAlign (torchvision, aligned=false, sampling_ratio=2).
// R5: scheduling fix. R4 showed 30% occupancy with no pipe saturated: the 750
// slow pixel blocks (L1,L0) drained LAST at ~3 blocks/CU while the 1800 fast
// strip blocks finished early. Changes: (a) CC 32->16 => 5100 blocks (~20/CU)
// for fine-grained packing; (b) heavy-first order L0,L1 pixels then L2,L3
// strips so the tail is made of many cheap strip blocks; (c) launch_bounds
// (256,8) pins VGPR<=64 => full 8 blocks/CU residency.

#define C_CH 256
#define CC 16                 // channels per thread
#define NCHUNK (C_CH / CC)

struct Params {
    const float* feat[4];
    const float* boxes;
    long long outBase[4];     // element offset into out (reference order L0..L3)
    float scale[4];
    int workBase[5];          // cumulative padded work items, kernel order L0,L1,L2,L3
    int M;
};

// ---------------- pixel path (levels 0,1) — R2 structure ----------------
template<int pSh, int hwSh>
__device__ __forceinline__ void pixel_body(
    const float* __restrict__ feat, const float* __restrict__ boxes,
    float* __restrict__ out, int r, int M, float sc)
{
    constexpr int HW = 1 << hwSh, HW2 = HW * HW, K = 1 << (2 * pSh);
    const int pixN = M << (2 * pSh);
    if (r >= pixN * NCHUNK) return;
    const int chunk = r / pixN;
    const int pix = r - chunk * pixN;
    const int m   = pix >> (2 * pSh);
    const int pib = pix & (K - 1);
    const int py  = pib >> pSh;
    const int px  = pib & ((1 << pSh) - 1);

    const float* bxp = boxes + m * 5;
    const int   b   = (int)bxp[0];
    const float rx1 = bxp[1] * sc, ry1 = bxp[2] * sc;
    const float rx2 = bxp[3] * sc, ry2 = bxp[4] * sc;
    const float invP  = 1.0f / (float)(1 << pSh);
    const float bin_w = fmaxf(rx2 - rx1, 1.0f) * invP;
    const float bin_h = fmaxf(ry2 - ry1, 1.0f) * invP;

    int off[16]; float w[16];
    #pragma unroll
    for (int qy = 0; qy < 2; ++qy) {
        float ys = ry1 + ((float)py + (qy ? 0.75f : 0.25f)) * bin_h;
        bool vy = (ys >= -1.0f) && (ys <= (float)HW);
        float y = fminf(fmaxf(ys, 0.0f), (float)(HW - 1));
        int y0 = (int)y, y1i = min(y0 + 1, HW - 1);
        float ly = y - (float)y0, hy = 1.0f - ly;
        #pragma unroll
        for (int qx = 0; qx < 2; ++qx) {
            float xs = rx1 + ((float)px + (qx ? 0.75f : 0.25f)) * bin_w;
            bool vx = (xs >= -1.0f) && (xs <= (float)HW);
            float x = fminf(fmaxf(xs, 0.0f), (float)(HW - 1));
            int x0 = (int)x, x1i = min(x0 + 1, HW - 1);
            float lx = x - (float)x0, hx = 1.0f - lx;
            float vw = (vy && vx) ? 0.25f : 0.0f;
            int s = (qy * 2 + qx) * 4;
            off[s + 0] = (y0  << hwSh) + x0;   w[s + 0] = vw * hy * hx;
            off[s + 1] = (y0  << hwSh) + x1i;  w[s + 1] = vw * hy * lx;
            off[s + 2] = (y1i << hwSh) + x0;   w[s + 2] = vw * ly * hx;
            off[s + 3] = (y1i << hwSh) + x1i;  w[s + 3] = vw * ly * lx;
        }
    }

    const float* fb = feat + (size_t)(b * C_CH + chunk * CC) * HW2;
    float* ob = out + (size_t)(m * C_CH + chunk * CC) * K + pib;
    #pragma unroll 2
    for (int c = 0; c < CC; ++c) {
        const float* fc = fb + c * HW2;
        float acc = 0.0f;
        #pragma unroll
        for (int i = 0; i < 16; ++i) acc += w[i] * fc[off[i]];
        ob[(size_t)c * K] = acc;
    }
}

// ---------------- strip-separable path (levels 2,3) ----------------
// S consecutive x-pixels (same py) share a 3-row x WC-col feature window.
template<int pSh, int hwSh, int S, int WC>
__device__ __forceinline__ void strip_body(
    const float* __restrict__ feat, const float* __restrict__ boxes,
    float* __restrict__ out, int r, int M, float sc)
{
    constexpr int HW = 1 << hwSh, HW2 = HW * HW, P = 1 << pSh, K = P * P;
    constexpr int NS = K / S;                 // strips per (m)
    static_assert(P / S == 4, "4 strips per row assumed");
    constexpr int lgNS = (NS == 128) ? 7 : (NS == 64 ? 6 : (NS == 32 ? 5 : 0));
    static_assert((1 << lgNS) == NS, "NS pow2");

    const int pixN = M * NS;
    if (r >= pixN * NCHUNK) return;
    const int chunk = r / pixN;
    const int t2    = r - chunk * pixN;
    const int m     = t2 >> lgNS;
    const int strip = t2 & (NS - 1);
    const int py    = strip >> 2;
    const int px0   = (strip & 3) * S;

    const float* bxp = boxes + m * 5;
    const int   b   = (int)bxp[0];
    const float rx1 = bxp[1] * sc, ry1 = bxp[2] * sc;
    const float rx2 = bxp[3] * sc, ry2 = bxp[4] * sc;
    const float invP  = 1.0f / (float)P;
    const float bin_w = fmaxf(rx2 - rx1, 1.0f) * invP;
    const float bin_h = fmaxf(ry2 - ry1, 1.0f) * invP;

    // Y weights (shared across the strip): 3-row window starting at rb.
    float WY[3] = {0.0f, 0.0f, 0.0f};
    int rb;
    {
        float ysf = ry1 + ((float)py + 0.25f) * bin_h;
        float yf  = fminf(fmaxf(ysf, 0.0f), (float)(HW - 1));
        rb = min((int)yf, HW - 3);
        #pragma unroll
        for (int qy = 0; qy < 2; ++qy) {
            float ys = ry1 + ((float)py + (qy ? 0.75f : 0.25f)) * bin_h;
            bool vy = (ys >= -1.0f) && (ys <= (float)HW);
            float y = fminf(fmaxf(ys, 0.0f), (float)(HW - 1));
            int y0 = (int)y, y1i = min(y0 + 1, HW - 1);
            float ly = y - (float)y0;
            float w0 = vy ? 0.5f * (1.0f - ly) : 0.0f;   // 0.5 = mean over 2 qy
            float w1 = vy ? 0.5f * ly          : 0.0f;
            int s0 = y0 - rb, s1 = y1i - rb;
            #pragma unroll
            for (int j = 0; j < 3; ++j)
                WY[j] += (s0 == j ? w0 : 0.0f) + (s1 == j ? w1 : 0.0f);
        }
    }

    // X weights per strip pixel: WC-col window starting at cb.
    float WX[S][WC];
    int cb;
    {
        float xsf = rx1 + ((float)px0 + 0.25f) * bin_w;
        float xf  = fminf(fmaxf(xsf, 0.0f), (float)(HW - 1));
        cb = min((int)xf, HW - WC);
        #pragma unroll
        for (int s = 0; s < S; ++s) {
            #pragma unroll
            for (int i = 0; i < WC; ++i) WX[s][i] = 0.0f;
            #pragma unroll
            for (int qx = 0; qx < 2; ++qx) {
                float xs = rx1 + ((float)(px0 + s) + (qx ? 0.75f : 0.25f)) * bin_w;
                bool vx = (xs >= -1.0f) && (xs <= (float)HW);
                float x = fminf(fmaxf(xs, 0.0f), (float)(HW - 1));
                int x0 = (int)x, x1i = min(x0 + 1, HW - 1);
                float lx = x - (float)x0;
                float w0 = vx ? 0.5f * (1.0f - lx) : 0.0f; // 0.5 = mean over 2 qx
                float w1 = vx ? 0.5f * lx          : 0.0f;
                int s0 = x0 - cb, s1 = x1i - cb;
                #pragma unroll
                for (int i = 0; i < WC; ++i)
                    WX[s][i] += (s0 == i ? w0 : 0.0f) + (s1 == i ? w1 : 0.0f);
            }
        }
    }

    const float* pf = feat + (size_t)((b * C_CH + chunk * CC) * HW2 + rb * HW + cb);
    float* po = out + (size_t)(((m * C_CH + chunk * CC) << (2 * pSh)) + (py << pSh) + px0);

    #pragma unroll 2
    for (int c = 0; c < CC; ++c) {
        float f[3][WC];
        #pragma unroll
        for (int j = 0; j < 3; ++j)
            #pragma unroll
            for (int i = 0; i < WC; ++i)
                f[j][i] = pf[j * HW + i];          // offset-folded dword loads

        float acc[S];
        #pragma unroll
        for (int s = 0; s < S; ++s) acc[s] = 0.0f;
        #pragma unroll
        for (int j = 0; j < 3; ++j) {
            #pragma unroll
            for (int s = 0; s < S; ++s) {
                float rs = 0.0f;
                #pragma unroll
                for (int i = 0; i < WC; ++i) rs += WX[s][i] * f[j][i];
                acc[s] += WY[j] * rs;
            }
        }
        #pragma unroll
        for (int s = 0; s < S; s += 4)             // px0 multiple of 4 -> 16B aligned
            *(float4*)(po + s) = make_float4(acc[s], acc[s+1], acc[s+2], acc[s+3]);
        pf += HW2;
        po += K;
    }
}

__global__ __launch_bounds__(256, 8) void msroi_kernel(Params p, float* __restrict__ out)
{
    const int blockStart = blockIdx.x * 256;      // blocks never straddle levels
    const int lvl = (blockStart >= p.workBase[1])
                  + (blockStart >= p.workBase[2])
                  + (blockStart >= p.workBase[3]);
    const int r = blockStart + (int)threadIdx.x - p.workBase[lvl];
    // kernel work order (heavy-first): 0->L0 pixels, 1->L1 pixels,
    //                                  2->L2 strips, 3->L3 strips
    if (lvl == 0)
        pixel_body<2, 7>(p.feat[0], p.boxes, out + p.outBase[0], r, p.M, p.scale[0]);
    else if (lvl == 1)
        pixel_body<3, 6>(p.feat[1], p.boxes, out + p.outBase[1], r, p.M, p.scale[1]);
    else if (lvl == 2)
        strip_body<4, 5, 4, 5>(p.feat[2], p.boxes, out + p.outBase[2], r, p.M, p.scale[2]);
    else
        strip_body<5, 4, 8, 4>(p.feat[3], p.boxes, out + p.outBase[3], r, p.M, p.scale[3]);
}

extern "C" void kernel_launch(void* const* d_in, const int* in_sizes, int n_in,
                              void* d_out, int out_size, void* d_ws, size_t ws_size,
                              hipStream_t stream) {
    const int M = in_sizes[4] / 5;

    Params p;
    p.feat[0] = (const float*)d_in[0];  // [2,256,128,128]
    p.feat[1] = (const float*)d_in[1];  // [2,256,64,64]
    p.feat[2] = (const float*)d_in[2];  // [2,256,32,32]
    p.feat[3] = (const float*)d_in[3];  // [2,256,16,16]
    p.boxes   = (const float*)d_in[4];
    p.M = M;
    const float scales[4] = {0.125f, 0.0625f, 0.03125f, 0.015625f};
    for (int l = 0; l < 4; ++l) p.scale[l] = scales[l];

    // Output bases in reference return order (L0..L3).
    p.outBase[0] = 0;
    p.outBase[1] = p.outBase[0] + (long long)M * C_CH * 4 * 4;
    p.outBase[2] = p.outBase[1] + (long long)M * C_CH * 8 * 8;
    p.outBase[3] = p.outBase[2] + (long long)M * C_CH * 16 * 16;

    // Work sizes, kernel order L0,L1 (pixels), L2 (strips of 4), L3 (strips of 8).
    const int work[4] = {
        M * NCHUNK * (4 * 4),         // L0 pixels
        M * NCHUNK * (8 * 8),         // L1 pixels
        M * NCHUNK * (16 * 16 / 4),   // L2 strips
        M * NCHUNK * (32 * 32 / 8)    // L3 strips
    };
    p.workBase[0] = 0;
    for (int i = 0; i < 4; ++i)
        p.workBase[i + 1] = p.workBase[i] + ((work[i] + 255) & ~255);

    const int blocks = p.workBase[4] / 256;
    msroi_kernel<<<blocks, 256, 0, stream>>>(p, (float*)d_out);
}

// Round 7
// 213.637 us; speedup vs baseline: 3.9881x; 3.9881x over previous
//
#include <hip/hip_runtime.h>
#include <stdint.h>

// Fused multi-scale ROIAlign (torchvision, aligned=false, sampling_ratio=2).
// R7 = R6 with the compile fix (__builtin_nontemporal_store needs a native
// vector type, not HIP's float4 class -> use ext_vector_type(4) float).
//  - launch_bounds(256,4): R4 proved VGPR=64, no spills, full 8 blocks/CU.
//    (R5's (256,8) forced VGPR=32 -> scratch spills -> 3.6 GB TCC traffic.)
//  - heavy-first block order: L0,L1 pixel blocks (gather-heavy) first;
//    3600 strip blocks are cheap + fine-grained and form the drain tail.
//  - nontemporal stores: 408 MB write-once output must not evict the gather
//    working set from L2 (FETCH=110MB proves L2 reuse carries the gathers).

#define C_CH 256
#define CC 32                 // channels per thread
#define NCHUNK (C_CH / CC)

typedef float vfloat4 __attribute__((ext_vector_type(4)));

struct Params {
    const float* feat[4];
    const float* boxes;
    long long outBase[4];     // element offset into out (reference order L0..L3)
    float scale[4];
    int workBase[5];          // cumulative padded work items, kernel order L0,L1,L2,L3
    int M;
};

// ---------------- pixel path (levels 0,1) — R2 structure ----------------
template<int pSh, int hwSh>
__device__ __forceinline__ void pixel_body(
    const float* __restrict__ feat, const float* __restrict__ boxes,
    float* __restrict__ out, int r, int M, float sc)
{
    constexpr int HW = 1 << hwSh, HW2 = HW * HW, K = 1 << (2 * pSh);
    const int pixN = M << (2 * pSh);
    if (r >= pixN * NCHUNK) return;
    const int chunk = r / pixN;
    const int pix = r - chunk * pixN;
    const int m   = pix >> (2 * pSh);
    const int pib = pix & (K - 1);
    const int py  = pib >> pSh;
    const int px  = pib & ((1 << pSh) - 1);

    const float* bxp = boxes + m * 5;
    const int   b   = (int)bxp[0];
    const float rx1 = bxp[1] * sc, ry1 = bxp[2] * sc;
    const float rx2 = bxp[3] * sc, ry2 = bxp[4] * sc;
    const float invP  = 1.0f / (float)(1 << pSh);
    const float bin_w = fmaxf(rx2 - rx1, 1.0f) * invP;
    const float bin_h = fmaxf(ry2 - ry1, 1.0f) * invP;

    int off[16]; float w[16];
    #pragma unroll
    for (int qy = 0; qy < 2; ++qy) {
        float ys = ry1 + ((float)py + (qy ? 0.75f : 0.25f)) * bin_h;
        bool vy = (ys >= -1.0f) && (ys <= (float)HW);
        float y = fminf(fmaxf(ys, 0.0f), (float)(HW - 1));
        int y0 = (int)y, y1i = min(y0 + 1, HW - 1);
        float ly = y - (float)y0, hy = 1.0f - ly;
        #pragma unroll
        for (int qx = 0; qx < 2; ++qx) {
            float xs = rx1 + ((float)px + (qx ? 0.75f : 0.25f)) * bin_w;
            bool vx = (xs >= -1.0f) && (xs <= (float)HW);
            float x = fminf(fmaxf(xs, 0.0f), (float)(HW - 1));
            int x0 = (int)x, x1i = min(x0 + 1, HW - 1);
            float lx = x - (float)x0, hx = 1.0f - lx;
            float vw = (vy && vx) ? 0.25f : 0.0f;
            int s = (qy * 2 + qx) * 4;
            off[s + 0] = (y0  << hwSh) + x0;   w[s + 0] = vw * hy * hx;
            off[s + 1] = (y0  << hwSh) + x1i;  w[s + 1] = vw * hy * lx;
            off[s + 2] = (y1i << hwSh) + x0;   w[s + 2] = vw * ly * hx;
            off[s + 3] = (y1i << hwSh) + x1i;  w[s + 3] = vw * ly * lx;
        }
    }

    const float* fb = feat + (size_t)(b * C_CH + chunk * CC) * HW2;
    float* ob = out + (size_t)(m * C_CH + chunk * CC) * K + pib;
    #pragma unroll 2
    for (int c = 0; c < CC; ++c) {
        const float* fc = fb + c * HW2;
        float acc = 0.0f;
        #pragma unroll
        for (int i = 0; i < 16; ++i) acc += w[i] * fc[off[i]];
        __builtin_nontemporal_store(acc, ob + (size_t)c * K);
    }
}

// ---------------- strip-separable path (levels 2,3) ----------------
// S consecutive x-pixels (same py) share a 3-row x WC-col feature window.
template<int pSh, int hwSh, int S, int WC>
__device__ __forceinline__ void strip_body(
    const float* __restrict__ feat, const float* __restrict__ boxes,
    float* __restrict__ out, int r, int M, float sc)
{
    constexpr int HW = 1 << hwSh, HW2 = HW * HW, P = 1 << pSh, K = P * P;
    constexpr int NS = K / S;                 // strips per (m)
    static_assert(P / S == 4, "4 strips per row assumed");
    constexpr int lgNS = (NS == 128) ? 7 : (NS == 64 ? 6 : (NS == 32 ? 5 : 0));
    static_assert((1 << lgNS) == NS, "NS pow2");

    const int pixN = M * NS;
    if (r >= pixN * NCHUNK) return;
    const int chunk = r / pixN;
    const int t2    = r - chunk * pixN;
    const int m     = t2 >> lgNS;
    const int strip = t2 & (NS - 1);
    const int py    = strip >> 2;
    const int px0   = (strip & 3) * S;

    const float* bxp = boxes + m * 5;
    const int   b   = (int)bxp[0];
    const float rx1 = bxp[1] * sc, ry1 = bxp[2] * sc;
    const float rx2 = bxp[3] * sc, ry2 = bxp[4] * sc;
    const float invP  = 1.0f / (float)P;
    const float bin_w = fmaxf(rx2 - rx1, 1.0f) * invP;
    const float bin_h = fmaxf(ry2 - ry1, 1.0f) * invP;

    // Y weights (shared across the strip): 3-row window starting at rb.
    float WY[3] = {0.0f, 0.0f, 0.0f};
    int rb;
    {
        float ysf = ry1 + ((float)py + 0.25f) * bin_h;
        float yf  = fminf(fmaxf(ysf, 0.0f), (float)(HW - 1));
        rb = min((int)yf, HW - 3);
        #pragma unroll
        for (int qy = 0; qy < 2; ++qy) {
            float ys = ry1 + ((float)py + (qy ? 0.75f : 0.25f)) * bin_h;
            bool vy = (ys >= -1.0f) && (ys <= (float)HW);
            float y = fminf(fmaxf(ys, 0.0f), (float)(HW - 1));
            int y0 = (int)y, y1i = min(y0 + 1, HW - 1);
            float ly = y - (float)y0;
            float w0 = vy ? 0.5f * (1.0f - ly) : 0.0f;   // 0.5 = mean over 2 qy
            float w1 = vy ? 0.5f * ly          : 0.0f;
            int s0 = y0 - rb, s1 = y1i - rb;
            #pragma unroll
            for (int j = 0; j < 3; ++j)
                WY[j] += (s0 == j ? w0 : 0.0f) + (s1 == j ? w1 : 0.0f);
        }
    }

    // X weights per strip pixel: WC-col window starting at cb.
    float WX[S][WC];
    int cb;
    {
        float xsf = rx1 + ((float)px0 + 0.25f) * bin_w;
        float xf  = fminf(fmaxf(xsf, 0.0f), (float)(HW - 1));
        cb = min((int)xf, HW - WC);
        #pragma unroll
        for (int s = 0; s < S; ++s) {
            #pragma unroll
            for (int i = 0; i < WC; ++i) WX[s][i] = 0.0f;
            #pragma unroll
            for (int qx = 0; qx < 2; ++qx) {
                float xs = rx1 + ((float)(px0 + s) + (qx ? 0.75f : 0.25f)) * bin_w;
                bool vx = (xs >= -1.0f) && (xs <= (float)HW);
                float x = fminf(fmaxf(xs, 0.0f), (float)(HW - 1));
                int x0 = (int)x, x1i = min(x0 + 1, HW - 1);
                float lx = x - (float)x0;
                float w0 = vx ? 0.5f * (1.0f - lx) : 0.0f; // 0.5 = mean over 2 qx
                float w1 = vx ? 0.5f * lx          : 0.0f;
                int s0 = x0 - cb, s1 = x1i - cb;
                #pragma unroll
                for (int i = 0; i < WC; ++i)
                    WX[s][i] += (s0 == i ? w0 : 0.0f) + (s1 == i ? w1 : 0.0f);
            }
        }
    }

    const float* pf = feat + (size_t)((b * C_CH + chunk * CC) * HW2 + rb * HW + cb);
    float* po = out + (size_t)(((m * C_CH + chunk * CC) << (2 * pSh)) + (py << pSh) + px0);

    #pragma unroll 2
    for (int c = 0; c < CC; ++c) {
        float f[3][WC];
        #pragma unroll
        for (int j = 0; j < 3; ++j)
            #pragma unroll
            for (int i = 0; i < WC; ++i)
                f[j][i] = pf[j * HW + i];          // offset-folded dword loads

        float acc[S];
        #pragma unroll
        for (int s = 0; s < S; ++s) acc[s] = 0.0f;
        #pragma unroll
        for (int j = 0; j < 3; ++j) {
            #pragma unroll
            for (int s = 0; s < S; ++s) {
                float rs = 0.0f;
                #pragma unroll
                for (int i = 0; i < WC; ++i) rs += WX[s][i] * f[j][i];
                acc[s] += WY[j] * rs;
            }
        }
        #pragma unroll
        for (int s = 0; s < S; s += 4) {           // px0 multiple of 4 -> 16B aligned
            vfloat4 v = {acc[s], acc[s+1], acc[s+2], acc[s+3]};
            __builtin_nontemporal_store(v, (vfloat4*)(po + s));
        }
        pf += HW2;
        po += K;
    }
}

__global__ __launch_bounds__(256, 4) void msroi_kernel(Params p, float* __restrict__ out)
{
    const int blockStart = blockIdx.x * 256;      // blocks never straddle levels
    const int lvl = (blockStart >= p.workBase[1])
                  + (blockStart >= p.workBase[2])
                  + (blockStart >= p.workBase[3]);
    const int r = blockStart + (int)threadIdx.x - p.workBase[lvl];
    // kernel work order (heavy-first): 0->L0 pixels, 1->L1 pixels,
    //                                  2->L2 strips, 3->L3 strips
    if (lvl == 0)
        pixel_body<2, 7>(p.feat[0], p.boxes, out + p.outBase[0], r, p.M, p.scale[0]);
    else if (lvl == 1)
        pixel_body<3, 6>(p.feat[1], p.boxes, out + p.outBase[1], r, p.M, p.scale[1]);
    else if (lvl == 2)
        strip_body<4, 5, 4, 5>(p.feat[2], p.boxes, out + p.outBase[2], r, p.M, p.scale[2]);
    else
        strip_body<5, 4, 8, 4>(p.feat[3], p.boxes, out + p.outBase[3], r, p.M, p.scale[3]);
}

extern "C" void kernel_launch(void* const* d_in, const int* in_sizes, int n_in,
                              void* d_out, int out_size, void* d_ws, size_t ws_size,
                              hipStream_t stream) {
    const int M = in_sizes[4] / 5;

    Params p;
    p.feat[0] = (const float*)d_in[0];  // [2,256,128,128]
    p.feat[1] = (const float*)d_in[1];  // [2,256,64,64]
    p.feat[2] = (const float*)d_in[2];  // [2,256,32,32]
    p.feat[3] = (const float*)d_in[3];  // [2,256,16,16]
    p.boxes   = (const float*)d_in[4];
    p.M = M;
    const float scales[4] = {0.125f, 0.0625f, 0.03125f, 0.015625f};
    for (int l = 0; l < 4; ++l) p.scale[l] = scales[l];

    // Output bases in reference return order (L0..L3).
    p.outBase[0] = 0;
    p.outBase[1] = p.outBase[0] + (long long)M * C_CH * 4 * 4;
    p.outBase[2] = p.outBase[1] + (long long)M * C_CH * 8 * 8;
    p.outBase[3] = p.outBase[2] + (long long)M * C_CH * 16 * 16;

    // Work sizes, kernel order L0,L1 (pixels), L2 (strips of 4), L3 (strips of 8).
    const int work[4] = {
        M * NCHUNK * (4 * 4),         // L0 pixels
        M * NCHUNK * (8 * 8),         // L1 pixels
        M * NCHUNK * (16 * 16 / 4),   // L2 strips
        M * NCHUNK * (32 * 32 / 8)    // L3 strips
    };
    p.workBase[0] = 0;
    for (int i = 0; i < 4; ++i)
        p.workBase[i + 1] = p.workBase[i] + ((work[i] + 255) & ~255);

    const int blocks = p.workBase[4] / 256;
    msroi_kernel<<<blocks, 256, 0, stream>>>(p, (float*)d_out);
}

// Round 8
// 194.078 us; speedup vs baseline: 4.3900x; 1.1008x over previous
//
#include <hip/hip_runtime.h>
#include <stdint.h>

// Fused multi-scale ROIAlign (torchvision, aligned=false, sampling_ratio=2).
// R8 = R7 + x-paired 8B gathers in the pixel path (isolated re-test of R3's
// confounded change). Theory: binding resource is L1/TA line-visit throughput
// (~115M line-visits ~= 190us; VALU/HBM/occupancy all unsaturated). The
// (x0,x0+1) taps share a cache line; pairing halves both gather instructions
// (16->8) and line visits for L0/L1. Everything else identical to R7:
//  - strip-separable L2/L3, heavy-first order, launch_bounds(256,4),
//    nontemporal stores (keep 408MB of write-once data out of L2).

#define C_CH 256
#define CC 32                 // channels per thread
#define NCHUNK (C_CH / CC)

typedef float vfloat4 __attribute__((ext_vector_type(4)));

struct F2 { float x, y; };    // align 4 (proven correct in R3); compiler picks codegen

struct Params {
    const float* feat[4];
    const float* boxes;
    long long outBase[4];     // element offset into out (reference order L0..L3)
    float scale[4];
    int workBase[5];          // cumulative padded work items, kernel order L0,L1,L2,L3
    int M;
};

// ---------------- pixel path (levels 0,1) — paired-tap gathers ----------------
template<int pSh, int hwSh>
__device__ __forceinline__ void pixel_body(
    const float* __restrict__ feat, const float* __restrict__ boxes,
    float* __restrict__ out, int r, int M, float sc)
{
    constexpr int HW = 1 << hwSh, HW2 = HW * HW, K = 1 << (2 * pSh);
    const int pixN = M << (2 * pSh);
    if (r >= pixN * NCHUNK) return;
    const int chunk = r / pixN;
    const int pix = r - chunk * pixN;
    const int m   = pix >> (2 * pSh);
    const int pib = pix & (K - 1);
    const int py  = pib >> pSh;
    const int px  = pib & ((1 << pSh) - 1);

    const float* bxp = boxes + m * 5;
    const int   b   = (int)bxp[0];
    const float rx1 = bxp[1] * sc, ry1 = bxp[2] * sc;
    const float rx2 = bxp[3] * sc, ry2 = bxp[4] * sc;
    const float invP  = 1.0f / (float)(1 << pSh);
    const float bin_w = fmaxf(rx2 - rx1, 1.0f) * invP;
    const float bin_h = fmaxf(ry2 - ry1, 1.0f) * invP;

    // 8 paired taps: per (qy,qx) sample, rows y0/y1i, cols (xb, xb+1).
    int off[8]; float wlo[8], whi[8];
    #pragma unroll
    for (int qy = 0; qy < 2; ++qy) {
        float ys = ry1 + ((float)py + (qy ? 0.75f : 0.25f)) * bin_h;
        bool vy = (ys >= -1.0f) && (ys <= (float)HW);
        float y = fminf(fmaxf(ys, 0.0f), (float)(HW - 1));
        int y0 = (int)y, y1i = min(y0 + 1, HW - 1);
        float ly = y - (float)y0, hy = 1.0f - ly;
        #pragma unroll
        for (int qx = 0; qx < 2; ++qx) {
            float xs = rx1 + ((float)px + (qx ? 0.75f : 0.25f)) * bin_w;
            bool vx = (xs >= -1.0f) && (xs <= (float)HW);
            float x = fminf(fmaxf(xs, 0.0f), (float)(HW - 1));
            int x0 = (int)x;
            float lx = x - (float)x0, hx = 1.0f - lx;
            // pair base clamped so the 8B read stays in-row; when clamped,
            // x0==HW-1 and lx==0, so the hi slot carries hx exactly.
            int xb = min(x0, HW - 2);
            float wx0 = (x0 == xb) ? hx : 0.0f;
            float wx1 = (x0 == xb) ? lx : hx;
            float vw = (vy && vx) ? 0.25f : 0.0f;   // 2x2-sample mean folded in
            int s = (qy * 2 + qx) * 2;
            off[s]     = (y0  << hwSh) + xb;
            wlo[s]     = vw * hy * wx0;  whi[s]     = vw * hy * wx1;
            off[s + 1] = (y1i << hwSh) + xb;
            wlo[s + 1] = vw * ly * wx0;  whi[s + 1] = vw * ly * wx1;
        }
    }

    const float* fb = feat + (size_t)(b * C_CH + chunk * CC) * HW2;
    float* ob = out + (size_t)(m * C_CH + chunk * CC) * K + pib;
    #pragma unroll 2
    for (int c = 0; c < CC; ++c) {
        const float* fc = fb + c * HW2;
        float acc = 0.0f;
        #pragma unroll
        for (int i = 0; i < 8; ++i) {
            F2 v = *(const F2*)(fc + off[i]);
            acc += wlo[i] * v.x + whi[i] * v.y;
        }
        __builtin_nontemporal_store(acc, ob + (size_t)c * K);
    }
}

// ---------------- strip-separable path (levels 2,3) ----------------
// S consecutive x-pixels (same py) share a 3-row x WC-col feature window.
template<int pSh, int hwSh, int S, int WC>
__device__ __forceinline__ void strip_body(
    const float* __restrict__ feat, const float* __restrict__ boxes,
    float* __restrict__ out, int r, int M, float sc)
{
    constexpr int HW = 1 << hwSh, HW2 = HW * HW, P = 1 << pSh, K = P * P;
    constexpr int NS = K / S;                 // strips per (m)
    static_assert(P / S == 4, "4 strips per row assumed");
    constexpr int lgNS = (NS == 128) ? 7 : (NS == 64 ? 6 : (NS == 32 ? 5 : 0));
    static_assert((1 << lgNS) == NS, "NS pow2");

    const int pixN = M * NS;
    if (r >= pixN * NCHUNK) return;
    const int chunk = r / pixN;
    const int t2    = r - chunk * pixN;
    const int m     = t2 >> lgNS;
    const int strip = t2 & (NS - 1);
    const int py    = strip >> 2;
    const int px0   = (strip & 3) * S;

    const float* bxp = boxes + m * 5;
    const int   b   = (int)bxp[0];
    const float rx1 = bxp[1] * sc, ry1 = bxp[2] * sc;
    const float rx2 = bxp[3] * sc, ry2 = bxp[4] * sc;
    const float invP  = 1.0f / (float)P;
    const float bin_w = fmaxf(rx2 - rx1, 1.0f) * invP;
    const float bin_h = fmaxf(ry2 - ry1, 1.0f) * invP;

    // Y weights (shared across the strip): 3-row window starting at rb.
    float WY[3] = {0.0f, 0.0f, 0.0f};
    int rb;
    {
        float ysf = ry1 + ((float)py + 0.25f) * bin_h;
        float yf  = fminf(fmaxf(ysf, 0.0f), (float)(HW - 1));
        rb = min((int)yf, HW - 3);
        #pragma unroll
        for (int qy = 0; qy < 2; ++qy) {
            float ys = ry1 + ((float)py + (qy ? 0.75f : 0.25f)) * bin_h;
            bool vy = (ys >= -1.0f) && (ys <= (float)HW);
            float y = fminf(fmaxf(ys, 0.0f), (float)(HW - 1));
            int y0 = (int)y, y1i = min(y0 + 1, HW - 1);
            float ly = y - (float)y0;
            float w0 = vy ? 0.5f * (1.0f - ly) : 0.0f;   // 0.5 = mean over 2 qy
            float w1 = vy ? 0.5f * ly          : 0.0f;
            int s0 = y0 - rb, s1 = y1i - rb;
            #pragma unroll
            for (int j = 0; j < 3; ++j)
                WY[j] += (s0 == j ? w0 : 0.0f) + (s1 == j ? w1 : 0.0f);
        }
    }

    // X weights per strip pixel: WC-col window starting at cb.
    float WX[S][WC];
    int cb;
    {
        float xsf = rx1 + ((float)px0 + 0.25f) * bin_w;
        float xf  = fminf(fmaxf(xsf, 0.0f), (float)(HW - 1));
        cb = min((int)xf, HW - WC);
        #pragma unroll
        for (int s = 0; s < S; ++s) {
            #pragma unroll
            for (int i = 0; i < WC; ++i) WX[s][i] = 0.0f;
            #pragma unroll
            for (int qx = 0; qx < 2; ++qx) {
                float xs = rx1 + ((float)(px0 + s) + (qx ? 0.75f : 0.25f)) * bin_w;
                bool vx = (xs >= -1.0f) && (xs <= (float)HW);
                float x = fminf(fmaxf(xs, 0.0f), (float)(HW - 1));
                int x0 = (int)x, x1i = min(x0 + 1, HW - 1);
                float lx = x - (float)x0;
                float w0 = vx ? 0.5f * (1.0f - lx) : 0.0f; // 0.5 = mean over 2 qx
                float w1 = vx ? 0.5f * lx          : 0.0f;
                int s0 = x0 - cb, s1 = x1i - cb;
                #pragma unroll
                for (int i = 0; i < WC; ++i)
                    WX[s][i] += (s0 == i ? w0 : 0.0f) + (s1 == i ? w1 : 0.0f);
            }
        }
    }

    const float* pf = feat + (size_t)((b * C_CH + chunk * CC) * HW2 + rb * HW + cb);
    float* po = out + (size_t)(((m * C_CH + chunk * CC) << (2 * pSh)) + (py << pSh) + px0);

    #pragma unroll 2
    for (int c = 0; c < CC; ++c) {
        float f[3][WC];
        #pragma unroll
        for (int j = 0; j < 3; ++j)
            #pragma unroll
            for (int i = 0; i < WC; ++i)
                f[j][i] = pf[j * HW + i];          // offset-folded dword loads

        float acc[S];
        #pragma unroll
        for (int s = 0; s < S; ++s) acc[s] = 0.0f;
        #pragma unroll
        for (int j = 0; j < 3; ++j) {
            #pragma unroll
            for (int s = 0; s < S; ++s) {
                float rs = 0.0f;
                #pragma unroll
                for (int i = 0; i < WC; ++i) rs += WX[s][i] * f[j][i];
                acc[s] += WY[j] * rs;
            }
        }
        #pragma unroll
        for (int s = 0; s < S; s += 4) {           // px0 multiple of 4 -> 16B aligned
            vfloat4 v = {acc[s], acc[s+1], acc[s+2], acc[s+3]};
            __builtin_nontemporal_store(v, (vfloat4*)(po + s));
        }
        pf += HW2;
        po += K;
    }
}

__global__ __launch_bounds__(256, 4) void msroi_kernel(Params p, float* __restrict__ out)
{
    const int blockStart = blockIdx.x * 256;      // blocks never straddle levels
    const int lvl = (blockStart >= p.workBase[1])
                  + (blockStart >= p.workBase[2])
                  + (blockStart >= p.workBase[3]);
    const int r = blockStart + (int)threadIdx.x - p.workBase[lvl];
    // kernel work order (heavy-first): 0->L0 pixels, 1->L1 pixels,
    //                                  2->L2 strips, 3->L3 strips
    if (lvl == 0)
        pixel_body<2, 7>(p.feat[0], p.boxes, out + p.outBase[0], r, p.M, p.scale[0]);
    else if (lvl == 1)
        pixel_body<3, 6>(p.feat[1], p.boxes, out + p.outBase[1], r, p.M, p.scale[1]);
    else if (lvl == 2)
        strip_body<4, 5, 4, 5>(p.feat[2], p.boxes, out + p.outBase[2], r, p.M, p.scale[2]);
    else
        strip_body<5, 4, 8, 4>(p.feat[3], p.boxes, out + p.outBase[3], r, p.M, p.scale[3]);
}

extern "C" void kernel_launch(void* const* d_in, const int* in_sizes, int n_in,
                              void* d_out, int out_size, void* d_ws, size_t ws_size,
                              hipStream_t stream) {
    const int M = in_sizes[4] / 5;

    Params p;
    p.feat[0] = (const float*)d_in[0];  // [2,256,128,128]
    p.feat[1] = (const float*)d_in[1];  // [2,256,64,64]
    p.feat[2] = (const float*)d_in[2];  // [2,256,32,32]
    p.feat[3] = (const float*)d_in[3];  // [2,256,16,16]
    p.boxes   = (const float*)d_in[4];
    p.M = M;
    const float scales[4] = {0.125f, 0.0625f, 0.03125f, 0.015625f};
    for (int l = 0; l < 4; ++l) p.scale[l] = scales[l];

    // Output bases in reference return order (L0..L3).
    p.outBase[0] = 0;
    p.outBase[1] = p.outBase[0] + (long long)M * C_CH * 4 * 4;
    p.outBase[2] = p.outBase[1] + (long long)M * C_CH * 8 * 8;
    p.outBase[3] = p.outBase[2] + (long long)M * C_CH * 16 * 16;

    // Work sizes, kernel order L0,L1 (pixels), L2 (strips of 4), L3 (strips of 8).
    const int work[4] = {
        M * NCHUNK * (4 * 4),         // L0 pixels
        M * NCHUNK * (8 * 8),         // L1 pixels
        M * NCHUNK * (16 * 16 / 4),   // L2 strips
        M * NCHUNK * (32 * 32 / 8)    // L3 strips
    };
    p.workBase[0] = 0;
    for (int i = 0; i < 4; ++i)
        p.workBase[i + 1] = p.workBase[i] + ((work[i] + 255) & ~255);

    const int blocks = p.workBase[4] / 256;
    msroi_kernel<<<blocks, 256, 0, stream>>>(p, (float*)d_out);
}

// Round 9
// 192.858 us; speedup vs baseline: 4.4178x; 1.0063x over previous
//
#include <hip/hip_runtime.h>
#include <stdint.h>

// Fused multi-scale ROIAlign (torchvision, aligned=false, sampling_ratio=2).
// R9 = R8 + vectorized strip-window loads (discriminating experiment):
//   TA-instruction model says address-divergent VMEM instrs cost ~16cyc flat,
//   so L3/L2 strips' 12-15 scalar dword loads per ch-iter dominate (~110us of
//   TA time). Load each 3-row window row as ONE align-4 float4 (+1 dword for
//   WC=5) via the under-aligned-typedef idiom R8 validated with F2.
//   L3: 12->3 loads/ch-iter, L2: 15->6. Pixel path & everything else frozen.
// If line-visit model is right instead, this is ~neutral and R10 goes LDS.

#define C_CH 256
#define CC 32                 // channels per thread
#define NCHUNK (C_CH / CC)

typedef float vfloat4 __attribute__((ext_vector_type(4)));
typedef vfloat4 __attribute__((aligned(4))) vfloat4_u;   // under-aligned load type

struct F2 { float x, y; };    // align-4 8B pair (validated R3/R8)

struct Params {
    const float* feat[4];
    const float* boxes;
    long long outBase[4];     // element offset into out (reference order L0..L3)
    float scale[4];
    int workBase[5];          // cumulative padded work items, kernel order L0,L1,L2,L3
    int M;
};

// ---------------- pixel path (levels 0,1) — paired-tap gathers ----------------
template<int pSh, int hwSh>
__device__ __forceinline__ void pixel_body(
    const float* __restrict__ feat, const float* __restrict__ boxes,
    float* __restrict__ out, int r, int M, float sc)
{
    constexpr int HW = 1 << hwSh, HW2 = HW * HW, K = 1 << (2 * pSh);
    const int pixN = M << (2 * pSh);
    if (r >= pixN * NCHUNK) return;
    const int chunk = r / pixN;
    const int pix = r - chunk * pixN;
    const int m   = pix >> (2 * pSh);
    const int pib = pix & (K - 1);
    const int py  = pib >> pSh;
    const int px  = pib & ((1 << pSh) - 1);

    const float* bxp = boxes + m * 5;
    const int   b   = (int)bxp[0];
    const float rx1 = bxp[1] * sc, ry1 = bxp[2] * sc;
    const float rx2 = bxp[3] * sc, ry2 = bxp[4] * sc;
    const float invP  = 1.0f / (float)(1 << pSh);
    const float bin_w = fmaxf(rx2 - rx1, 1.0f) * invP;
    const float bin_h = fmaxf(ry2 - ry1, 1.0f) * invP;

    // 8 paired taps: per (qy,qx) sample, rows y0/y1i, cols (xb, xb+1).
    int off[8]; float wlo[8], whi[8];
    #pragma unroll
    for (int qy = 0; qy < 2; ++qy) {
        float ys = ry1 + ((float)py + (qy ? 0.75f : 0.25f)) * bin_h;
        bool vy = (ys >= -1.0f) && (ys <= (float)HW);
        float y = fminf(fmaxf(ys, 0.0f), (float)(HW - 1));
        int y0 = (int)y, y1i = min(y0 + 1, HW - 1);
        float ly = y - (float)y0, hy = 1.0f - ly;
        #pragma unroll
        for (int qx = 0; qx < 2; ++qx) {
            float xs = rx1 + ((float)px + (qx ? 0.75f : 0.25f)) * bin_w;
            bool vx = (xs >= -1.0f) && (xs <= (float)HW);
            float x = fminf(fmaxf(xs, 0.0f), (float)(HW - 1));
            int x0 = (int)x;
            float lx = x - (float)x0, hx = 1.0f - lx;
            int xb = min(x0, HW - 2);
            float wx0 = (x0 == xb) ? hx : 0.0f;
            float wx1 = (x0 == xb) ? lx : hx;
            float vw = (vy && vx) ? 0.25f : 0.0f;   // 2x2-sample mean folded in
            int s = (qy * 2 + qx) * 2;
            off[s]     = (y0  << hwSh) + xb;
            wlo[s]     = vw * hy * wx0;  whi[s]     = vw * hy * wx1;
            off[s + 1] = (y1i << hwSh) + xb;
            wlo[s + 1] = vw * ly * wx0;  whi[s + 1] = vw * ly * wx1;
        }
    }

    const float* fb = feat + (size_t)(b * C_CH + chunk * CC) * HW2;
    float* ob = out + (size_t)(m * C_CH + chunk * CC) * K + pib;
    #pragma unroll 2
    for (int c = 0; c < CC; ++c) {
        const float* fc = fb + c * HW2;
        float acc = 0.0f;
        #pragma unroll
        for (int i = 0; i < 8; ++i) {
            F2 v = *(const F2*)(fc + off[i]);
            acc += wlo[i] * v.x + whi[i] * v.y;
        }
        __builtin_nontemporal_store(acc, ob + (size_t)c * K);
    }
}

// ---------------- strip-separable path (levels 2,3) ----------------
// S consecutive x-pixels (same py) share a 3-row x WC-col feature window.
template<int pSh, int hwSh, int S, int WC>
__device__ __forceinline__ void strip_body(
    const float* __restrict__ feat, const float* __restrict__ boxes,
    float* __restrict__ out, int r, int M, float sc)
{
    constexpr int HW = 1 << hwSh, HW2 = HW * HW, P = 1 << pSh, K = P * P;
    constexpr int NS = K / S;                 // strips per (m)
    static_assert(P / S == 4, "4 strips per row assumed");
    static_assert(WC >= 4 && WC <= 8, "window 4..8 cols");
    constexpr int lgNS = (NS == 128) ? 7 : (NS == 64 ? 6 : (NS == 32 ? 5 : 0));
    static_assert((1 << lgNS) == NS, "NS pow2");

    const int pixN = M * NS;
    if (r >= pixN * NCHUNK) return;
    const int chunk = r / pixN;
    const int t2    = r - chunk * pixN;
    const int m     = t2 >> lgNS;
    const int strip = t2 & (NS - 1);
    const int py    = strip >> 2;
    const int px0   = (strip & 3) * S;

    const float* bxp = boxes + m * 5;
    const int   b   = (int)bxp[0];
    const float rx1 = bxp[1] * sc, ry1 = bxp[2] * sc;
    const float rx2 = bxp[3] * sc, ry2 = bxp[4] * sc;
    const float invP  = 1.0f / (float)P;
    const float bin_w = fmaxf(rx2 - rx1, 1.0f) * invP;
    const float bin_h = fmaxf(ry2 - ry1, 1.0f) * invP;

    // Y weights (shared across the strip): 3-row window starting at rb.
    float WY[3] = {0.0f, 0.0f, 0.0f};
    int rb;
    {
        float ysf = ry1 + ((float)py + 0.25f) * bin_h;
        float yf  = fminf(fmaxf(ysf, 0.0f), (float)(HW - 1));
        rb = min((int)yf, HW - 3);
        #pragma unroll
        for (int qy = 0; qy < 2; ++qy) {
            float ys = ry1 + ((float)py + (qy ? 0.75f : 0.25f)) * bin_h;
            bool vy = (ys >= -1.0f) && (ys <= (float)HW);
            float y = fminf(fmaxf(ys, 0.0f), (float)(HW - 1));
            int y0 = (int)y, y1i = min(y0 + 1, HW - 1);
            float ly = y - (float)y0;
            float w0 = vy ? 0.5f * (1.0f - ly) : 0.0f;   // 0.5 = mean over 2 qy
            float w1 = vy ? 0.5f * ly          : 0.0f;
            int s0 = y0 - rb, s1 = y1i - rb;
            #pragma unroll
            for (int j = 0; j < 3; ++j)
                WY[j] += (s0 == j ? w0 : 0.0f) + (s1 == j ? w1 : 0.0f);
        }
    }

    // X weights per strip pixel: WC-col window starting at cb.
    float WX[S][WC];
    int cb;
    {
        float xsf = rx1 + ((float)px0 + 0.25f) * bin_w;
        float xf  = fminf(fmaxf(xsf, 0.0f), (float)(HW - 1));
        cb = min((int)xf, HW - WC);
        #pragma unroll
        for (int s = 0; s < S; ++s) {
            #pragma unroll
            for (int i = 0; i < WC; ++i) WX[s][i] = 0.0f;
            #pragma unroll
            for (int qx = 0; qx < 2; ++qx) {
                float xs = rx1 + ((float)(px0 + s) + (qx ? 0.75f : 0.25f)) * bin_w;
                bool vx = (xs >= -1.0f) && (xs <= (float)HW);
                float x = fminf(fmaxf(xs, 0.0f), (float)(HW - 1));
                int x0 = (int)x, x1i = min(x0 + 1, HW - 1);
                float lx = x - (float)x0;
                float w0 = vx ? 0.5f * (1.0f - lx) : 0.0f; // 0.5 = mean over 2 qx
                float w1 = vx ? 0.5f * lx          : 0.0f;
                int s0 = x0 - cb, s1 = x1i - cb;
                #pragma unroll
                for (int i = 0; i < WC; ++i)
                    WX[s][i] += (s0 == i ? w0 : 0.0f) + (s1 == i ? w1 : 0.0f);
            }
        }
    }

    const float* pf = feat + (size_t)((b * C_CH + chunk * CC) * HW2 + rb * HW + cb);
    float* po = out + (size_t)(((m * C_CH + chunk * CC) << (2 * pSh)) + (py << pSh) + px0);

    #pragma unroll 2
    for (int c = 0; c < CC; ++c) {
        // Row-vectorized window load: one align-4 float4 per row + scalars
        // beyond col 3 (R9 change; was WC scalar dword loads per row).
        float f[3][WC];
        #pragma unroll
        for (int j = 0; j < 3; ++j) {
            vfloat4 r4 = *(const vfloat4_u*)(pf + j * HW);
            f[j][0] = r4.x; f[j][1] = r4.y; f[j][2] = r4.z; f[j][3] = r4.w;
            #pragma unroll
            for (int i = 4; i < WC; ++i) f[j][i] = pf[j * HW + i];
        }

        float acc[S];
        #pragma unroll
        for (int s = 0; s < S; ++s) acc[s] = 0.0f;
        #pragma unroll
        for (int j = 0; j < 3; ++j) {
            #pragma unroll
            for (int s = 0; s < S; ++s) {
                float rs = 0.0f;
                #pragma unroll
                for (int i = 0; i < WC; ++i) rs += WX[s][i] * f[j][i];
                acc[s] += WY[j] * rs;
            }
        }
        #pragma unroll
        for (int s = 0; s < S; s += 4) {           // px0 multiple of 4 -> 16B aligned
            vfloat4 v = {acc[s], acc[s+1], acc[s+2], acc[s+3]};
            __builtin_nontemporal_store(v, (vfloat4*)(po + s));
        }
        pf += HW2;
        po += K;
    }
}

__global__ __launch_bounds__(256, 4) void msroi_kernel(Params p, float* __restrict__ out)
{
    const int blockStart = blockIdx.x * 256;      // blocks never straddle levels
    const int lvl = (blockStart >= p.workBase[1])
                  + (blockStart >= p.workBase[2])
                  + (blockStart >= p.workBase[3]);
    const int r = blockStart + (int)threadIdx.x - p.workBase[lvl];
    // kernel work order (heavy-first): 0->L0 pixels, 1->L1 pixels,
    //                                  2->L2 strips, 3->L3 strips
    if (lvl == 0)
        pixel_body<2, 7>(p.feat[0], p.boxes, out + p.outBase[0], r, p.M, p.scale[0]);
    else if (lvl == 1)
        pixel_body<3, 6>(p.feat[1], p.boxes, out + p.outBase[1], r, p.M, p.scale[1]);
    else if (lvl == 2)
        strip_body<4, 5, 4, 5>(p.feat[2], p.boxes, out + p.outBase[2], r, p.M, p.scale[2]);
    else
        strip_body<5, 4, 8, 4>(p.feat[3], p.boxes, out + p.outBase[3], r, p.M, p.scale[3]);
}

extern "C" void kernel_launch(void* const* d_in, const int* in_sizes, int n_in,
                              void* d_out, int out_size, void* d_ws, size_t ws_size,
                              hipStream_t stream) {
    const int M = in_sizes[4] / 5;

    Params p;
    p.feat[0] = (const float*)d_in[0];  // [2,256,128,128]
    p.feat[1] = (const float*)d_in[1];  // [2,256,64,64]
    p.feat[2] = (const float*)d_in[2];  // [2,256,32,32]
    p.feat[3] = (const float*)d_in[3];  // [2,256,16,16]
    p.boxes   = (const float*)d_in[4];
    p.M = M;
    const float scales[4] = {0.125f, 0.0625f, 0.03125f, 0.015625f};
    for (int l = 0; l < 4; ++l) p.scale[l] = scales[l];

    // Output bases in reference return order (L0..L3).
    p.outBase[0] = 0;
    p.outBase[1] = p.outBase[0] + (long long)M * C_CH * 4 * 4;
    p.outBase[2] = p.outBase[1] + (long long)M * C_CH * 8 * 8;
    p.outBase[3] = p.outBase[2] + (long long)M * C_CH * 16 * 16;

    // Work sizes, kernel order L0,L1 (pixels), L2 (strips of 4), L3 (strips of 8).
    const int work[4] = {
        M * NCHUNK * (4 * 4),         // L0 pixels
        M * NCHUNK * (8 * 8),         // L1 pixels
        M * NCHUNK * (16 * 16 / 4),   // L2 strips
        M * NCHUNK * (32 * 32 / 8)    // L3 strips
    };
    p.workBase[0] = 0;
    for (int i = 0; i < 4; ++i)
        p.workBase[i + 1] = p.workBase[i] + ((work[i] + 255) & ~255);

    const int blocks = p.workBase[4] / 256;
    msroi_kernel<<<blocks, 256, 0, stream>>>(p, (float*)d_out);
}

// Round 10
// 186.616 us; speedup vs baseline: 4.5656x; 1.0334x over previous
//
#include <hip/hip_runtime.h>
#include <stdint.h>

// Fused multi-scale ROIAlign (torchvision, aligned=false, sampling_ratio=2).
// R10 = R9 + L1 converted to the strip path (S=2, 6 cols x 4 rows window).
// Line-visit model (confirmed by R8 win + R9 null): L1's pixel-path gathers
// were ~23M of ~47M total distinct-cache-line touches. Strip rows are shared
// across a wave's lanes (~24 lines/instr vs ~38), cutting L1 to ~7M.
// Strip template generalized with RC (rows) param; row-streaming accumulation
// keeps the window live-range to one row (6 floats) for low VGPR pressure.
// L0 remains pixel-path (bin<=9.4 -> window too wide for fixed-WC strips).

#define C_CH 256
#define CC 32                 // channels per thread
#define NCHUNK (C_CH / CC)

typedef float vfloat4 __attribute__((ext_vector_type(4)));
typedef vfloat4 __attribute__((aligned(4))) vfloat4_u;   // under-aligned 16B load
typedef float vfloat2 __attribute__((ext_vector_type(2)));

struct F2 { float x, y; };    // align-4 8B pair (validated R3/R8)

struct Params {
    const float* feat[4];
    const float* boxes;
    long long outBase[4];     // element offset into out (reference order L0..L3)
    float scale[4];
    int workBase[5];          // cumulative padded work items, kernel order L0,L1,L2,L3
    int M;
};

// ---------------- pixel path (level 0) — paired-tap gathers ----------------
template<int pSh, int hwSh>
__device__ __forceinline__ void pixel_body(
    const float* __restrict__ feat, const float* __restrict__ boxes,
    float* __restrict__ out, int r, int M, float sc)
{
    constexpr int HW = 1 << hwSh, HW2 = HW * HW, K = 1 << (2 * pSh);
    const int pixN = M << (2 * pSh);
    if (r >= pixN * NCHUNK) return;
    const int chunk = r / pixN;
    const int pix = r - chunk * pixN;
    const int m   = pix >> (2 * pSh);
    const int pib = pix & (K - 1);
    const int py  = pib >> pSh;
    const int px  = pib & ((1 << pSh) - 1);

    const float* bxp = boxes + m * 5;
    const int   b   = (int)bxp[0];
    const float rx1 = bxp[1] * sc, ry1 = bxp[2] * sc;
    const float rx2 = bxp[3] * sc, ry2 = bxp[4] * sc;
    const float invP  = 1.0f / (float)(1 << pSh);
    const float bin_w = fmaxf(rx2 - rx1, 1.0f) * invP;
    const float bin_h = fmaxf(ry2 - ry1, 1.0f) * invP;

    // 8 paired taps: per (qy,qx) sample, rows y0/y1i, cols (xb, xb+1).
    int off[8]; float wlo[8], whi[8];
    #pragma unroll
    for (int qy = 0; qy < 2; ++qy) {
        float ys = ry1 + ((float)py + (qy ? 0.75f : 0.25f)) * bin_h;
        bool vy = (ys >= -1.0f) && (ys <= (float)HW);
        float y = fminf(fmaxf(ys, 0.0f), (float)(HW - 1));
        int y0 = (int)y, y1i = min(y0 + 1, HW - 1);
        float ly = y - (float)y0, hy = 1.0f - ly;
        #pragma unroll
        for (int qx = 0; qx < 2; ++qx) {
            float xs = rx1 + ((float)px + (qx ? 0.75f : 0.25f)) * bin_w;
            bool vx = (xs >= -1.0f) && (xs <= (float)HW);
            float x = fminf(fmaxf(xs, 0.0f), (float)(HW - 1));
            int x0 = (int)x;
            float lx = x - (float)x0, hx = 1.0f - lx;
            int xb = min(x0, HW - 2);
            float wx0 = (x0 == xb) ? hx : 0.0f;
            float wx1 = (x0 == xb) ? lx : hx;
            float vw = (vy && vx) ? 0.25f : 0.0f;   // 2x2-sample mean folded in
            int s = (qy * 2 + qx) * 2;
            off[s]     = (y0  << hwSh) + xb;
            wlo[s]     = vw * hy * wx0;  whi[s]     = vw * hy * wx1;
            off[s + 1] = (y1i << hwSh) + xb;
            wlo[s + 1] = vw * ly * wx0;  whi[s + 1] = vw * ly * wx1;
        }
    }

    const float* fb = feat + (size_t)(b * C_CH + chunk * CC) * HW2;
    float* ob = out + (size_t)(m * C_CH + chunk * CC) * K + pib;
    #pragma unroll 2
    for (int c = 0; c < CC; ++c) {
        const float* fc = fb + c * HW2;
        float acc = 0.0f;
        #pragma unroll
        for (int i = 0; i < 8; ++i) {
            F2 v = *(const F2*)(fc + off[i]);
            acc += wlo[i] * v.x + whi[i] * v.y;
        }
        __builtin_nontemporal_store(acc, ob + (size_t)c * K);
    }
}

// ---------------- strip-separable path (levels 1,2,3) ----------------
// S consecutive x-pixels (same py) share an RC-row x WC-col feature window.
template<int pSh, int hwSh, int S, int WC, int RC>
__device__ __forceinline__ void strip_body(
    const float* __restrict__ feat, const float* __restrict__ boxes,
    float* __restrict__ out, int r, int M, float sc)
{
    constexpr int HW = 1 << hwSh, HW2 = HW * HW, P = 1 << pSh, K = P * P;
    constexpr int NS = K / S;                 // strips per (m)
    static_assert(P / S == 4, "4 strips per row assumed");
    static_assert(WC >= 4 && WC <= 6, "window 4..6 cols");
    constexpr int lgNS = (NS == 128) ? 7 : (NS == 64 ? 6 : (NS == 32 ? 5 : 0));
    static_assert((1 << lgNS) == NS, "NS pow2");

    const int pixN = M * NS;
    if (r >= pixN * NCHUNK) return;
    const int chunk = r / pixN;
    const int t2    = r - chunk * pixN;
    const int m     = t2 >> lgNS;
    const int strip = t2 & (NS - 1);
    const int py    = strip >> 2;
    const int px0   = (strip & 3) * S;

    const float* bxp = boxes + m * 5;
    const int   b   = (int)bxp[0];
    const float rx1 = bxp[1] * sc, ry1 = bxp[2] * sc;
    const float rx2 = bxp[3] * sc, ry2 = bxp[4] * sc;
    const float invP  = 1.0f / (float)P;
    const float bin_w = fmaxf(rx2 - rx1, 1.0f) * invP;
    const float bin_h = fmaxf(ry2 - ry1, 1.0f) * invP;

    // Y weights (shared across the strip): RC-row window starting at rb.
    float WY[RC];
    #pragma unroll
    for (int j = 0; j < RC; ++j) WY[j] = 0.0f;
    int rb;
    {
        float ysf = ry1 + ((float)py + 0.25f) * bin_h;
        float yf  = fminf(fmaxf(ysf, 0.0f), (float)(HW - 1));
        rb = min((int)yf, HW - RC);
        #pragma unroll
        for (int qy = 0; qy < 2; ++qy) {
            float ys = ry1 + ((float)py + (qy ? 0.75f : 0.25f)) * bin_h;
            bool vy = (ys >= -1.0f) && (ys <= (float)HW);
            float y = fminf(fmaxf(ys, 0.0f), (float)(HW - 1));
            int y0 = (int)y, y1i = min(y0 + 1, HW - 1);
            float ly = y - (float)y0;
            float w0 = vy ? 0.5f * (1.0f - ly) : 0.0f;   // 0.5 = mean over 2 qy
            float w1 = vy ? 0.5f * ly          : 0.0f;
            int s0 = y0 - rb, s1 = y1i - rb;
            #pragma unroll
            for (int j = 0; j < RC; ++j)
                WY[j] += (s0 == j ? w0 : 0.0f) + (s1 == j ? w1 : 0.0f);
        }
    }

    // X weights per strip pixel: WC-col window starting at cb.
    float WX[S][WC];
    int cb;
    {
        float xsf = rx1 + ((float)px0 + 0.25f) * bin_w;
        float xf  = fminf(fmaxf(xsf, 0.0f), (float)(HW - 1));
        cb = min((int)xf, HW - WC);
        #pragma unroll
        for (int s = 0; s < S; ++s) {
            #pragma unroll
            for (int i = 0; i < WC; ++i) WX[s][i] = 0.0f;
            #pragma unroll
            for (int qx = 0; qx < 2; ++qx) {
                float xs = rx1 + ((float)(px0 + s) + (qx ? 0.75f : 0.25f)) * bin_w;
                bool vx = (xs >= -1.0f) && (xs <= (float)HW);
                float x = fminf(fmaxf(xs, 0.0f), (float)(HW - 1));
                int x0 = (int)x, x1i = min(x0 + 1, HW - 1);
                float lx = x - (float)x0;
                float w0 = vx ? 0.5f * (1.0f - lx) : 0.0f; // 0.5 = mean over 2 qx
                float w1 = vx ? 0.5f * lx          : 0.0f;
                int s0 = x0 - cb, s1 = x1i - cb;
                #pragma unroll
                for (int i = 0; i < WC; ++i)
                    WX[s][i] += (s0 == i ? w0 : 0.0f) + (s1 == i ? w1 : 0.0f);
            }
        }
    }

    const float* pf = feat + (size_t)((b * C_CH + chunk * CC) * HW2 + rb * HW + cb);
    float* po = out + (size_t)(((m * C_CH + chunk * CC) << (2 * pSh)) + (py << pSh) + px0);

    #pragma unroll 2
    for (int c = 0; c < CC; ++c) {
        float acc[S];
        #pragma unroll
        for (int s = 0; s < S; ++s) acc[s] = 0.0f;

        // Row-streaming: load one row (vectorized), accumulate, discard.
        #pragma unroll
        for (int j = 0; j < RC; ++j) {
            float f[WC];
            vfloat4 r4 = *(const vfloat4_u*)(pf + j * HW);
            f[0] = r4.x; f[1] = r4.y; f[2] = r4.z; f[3] = r4.w;
            if constexpr (WC == 5) {
                f[4] = pf[j * HW + 4];
            } else if constexpr (WC == 6) {
                F2 t = *(const F2*)(pf + j * HW + 4);
                f[4] = t.x; f[5] = t.y;
            }
            #pragma unroll
            for (int s = 0; s < S; ++s) {
                float rs = 0.0f;
                #pragma unroll
                for (int i = 0; i < WC; ++i) rs += WX[s][i] * f[i];
                acc[s] += WY[j] * rs;
            }
        }

        if constexpr (S == 2) {                    // px0 even -> 8B aligned
            vfloat2 v = {acc[0], acc[1]};
            __builtin_nontemporal_store(v, (vfloat2*)po);
        } else {
            #pragma unroll
            for (int s = 0; s < S; s += 4) {       // px0 mult of 4 -> 16B aligned
                vfloat4 v = {acc[s], acc[s+1], acc[s+2], acc[s+3]};
                __builtin_nontemporal_store(v, (vfloat4*)(po + s));
            }
        }
        pf += HW2;
        po += K;
    }
}

__global__ __launch_bounds__(256, 4) void msroi_kernel(Params p, float* __restrict__ out)
{
    const int blockStart = blockIdx.x * 256;      // blocks never straddle levels
    const int lvl = (blockStart >= p.workBase[1])
                  + (blockStart >= p.workBase[2])
                  + (blockStart >= p.workBase[3]);
    const int r = blockStart + (int)threadIdx.x - p.workBase[lvl];
    // kernel work order (heavy-first): 0->L0 pixels, 1->L1 strips(S=2),
    //                                  2->L2 strips(S=4), 3->L3 strips(S=8)
    if (lvl == 0)
        pixel_body<2, 7>(p.feat[0], p.boxes, out + p.outBase[0], r, p.M, p.scale[0]);
    else if (lvl == 1)
        strip_body<3, 6, 2, 6, 4>(p.feat[1], p.boxes, out + p.outBase[1], r, p.M, p.scale[1]);
    else if (lvl == 2)
        strip_body<4, 5, 4, 5, 3>(p.feat[2], p.boxes, out + p.outBase[2], r, p.M, p.scale[2]);
    else
        strip_body<5, 4, 8, 4, 3>(p.feat[3], p.boxes, out + p.outBase[3], r, p.M, p.scale[3]);
}

extern "C" void kernel_launch(void* const* d_in, const int* in_sizes, int n_in,
                              void* d_out, int out_size, void* d_ws, size_t ws_size,
                              hipStream_t stream) {
    const int M = in_sizes[4] / 5;

    Params p;
    p.feat[0] = (const float*)d_in[0];  // [2,256,128,128]
    p.feat[1] = (const float*)d_in[1];  // [2,256,64,64]
    p.feat[2] = (const float*)d_in[2];  // [2,256,32,32]
    p.feat[3] = (const float*)d_in[3];  // [2,256,16,16]
    p.boxes   = (const float*)d_in[4];
    p.M = M;
    const float scales[4] = {0.125f, 0.0625f, 0.03125f, 0.015625f};
    for (int l = 0; l < 4; ++l) p.scale[l] = scales[l];

    // Output bases in reference return order (L0..L3).
    p.outBase[0] = 0;
    p.outBase[1] = p.outBase[0] + (long long)M * C_CH * 4 * 4;
    p.outBase[2] = p.outBase[1] + (long long)M * C_CH * 8 * 8;
    p.outBase[3] = p.outBase[2] + (long long)M * C_CH * 16 * 16;

    // Work sizes, kernel order L0 (pixels), L1 (strips of 2), L2 (4), L3 (8).
    const int work[4] = {
        M * NCHUNK * (4 * 4),         // L0 pixels
        M * NCHUNK * (8 * 8 / 2),     // L1 strips
        M * NCHUNK * (16 * 16 / 4),   // L2 strips
        M * NCHUNK * (32 * 32 / 8)    // L3 strips
    };
    p.workBase[0] = 0;
    for (int i = 0; i < 4; ++i)
        p.workBase[i + 1] = p.workBase[i] + ((work[i] + 255) & ~255);

    const int blocks = p.workBase[4] / 256;
    msroi_kernel<<<blocks, 256, 0, stream>>>(p, (float*)d_out);
}